// Round 1
// baseline (6081.703 us; speedup 1.0000x reference)
//
#include <hip/hip_runtime.h>
#include <hip/hip_bf16.h>
#include <stdint.h>

#define T_SEQ 512
#define HID   512
#define BATCH 128
#define G_B   2
#define G_N   32
#define BB    (BATCH / G_B)     // 64 batch rows per WG
#define HC    (HID / G_N)       // 16 h-cols per WG
#define NROW  (3 * HC)          // 48 W rows per matrix chunk
#define THREADS 256
#define HFIN  (BATCH * HID)     // h_final element count (65536)
#define WSTR  520               // LDS row stride in shorts (+8 pad -> 2-way-max bank alias)

using f32x4  = __attribute__((ext_vector_type(4))) float;
using short8 = __attribute__((ext_vector_type(8))) short;

__device__ __forceinline__ short8 pack8(float a0, float a1, float a2, float a3,
                                        float a4, float a5, float a6, float a7) {
    union { uint32_t u[4]; short8 s; } r;
    asm("v_cvt_pk_bf16_f32 %0, %1, %2" : "=v"(r.u[0]) : "v"(a0), "v"(a1));
    asm("v_cvt_pk_bf16_f32 %0, %1, %2" : "=v"(r.u[1]) : "v"(a2), "v"(a3));
    asm("v_cvt_pk_bf16_f32 %0, %1, %2" : "=v"(r.u[2]) : "v"(a4), "v"(a5));
    asm("v_cvt_pk_bf16_f32 %0, %1, %2" : "=v"(r.u[3]) : "v"(a6), "v"(a7));
    return r.s;
}

__device__ __forceinline__ uint16_t f2bf(float f) {  // RNE
    uint32_t u = __builtin_bit_cast(uint32_t, f);
    return (uint16_t)((u + 0x7fffu + ((u >> 16) & 1u)) >> 16);
}

__global__ void init_counters(int* cnt) {
    if (threadIdx.x < 64) cnt[threadIdx.x] = 0;
}

__global__ void __launch_bounds__(THREADS, 1) gru_scan(
    const float* __restrict__ hidden,   // [B][H]
    const float* __restrict__ ins,      // [B][T][H]
    const int*   __restrict__ resets,   // [B][T]
    const float* __restrict__ W_ih,     // [3H][H]
    const float* __restrict__ W_hh,     // [3H][H]
    const float* __restrict__ b_ih,     // [3H]
    const float* __restrict__ b_hh,     // [3H]
    float* __restrict__ out,            // [B*H] h_final, then [B][T][H] ys
    int* __restrict__ cnt)
{
    __shared__ __align__(16) short ldsW[2][NROW][WSTR];   // ~97.5 KB

    const int bb   = blockIdx.x >> 5;   // batch block 0..1
    const int nn   = blockIdx.x & 31;   // h-col chunk 0..31
    const int tid  = threadIdx.x;
    const int lane = tid & 63;
    const int wave = tid >> 6;          // M-tile index 0..3

    // ---- one-time: W chunks -> LDS (bf16), rows: gate g, local col i ----
    for (int idx = tid; idx < NROW * HID; idx += THREADS) {
        const int row = idx >> 9;              // 0..47
        const int k   = idx & (HID - 1);
        const int g   = row >> 4;              // 0..2 (r,z,n)
        const int i   = row & 15;
        const int grow = g * HID + nn * HC + i;
        ldsW[0][row][k] = (short)f2bf(W_ih[grow * HID + k]);
        ldsW[1][row][k] = (short)f2bf(W_hh[grow * HID + k]);
    }
    __syncthreads();

    const int l15   = lane & 15;
    const int lg    = lane >> 4;                       // 0..3
    const int arow  = bb * BB + wave * 16 + l15;       // global batch row (A operand)
    const int drow0 = bb * BB + wave * 16 + lg * 4;    // global batch row base (D side)
    const int dcol  = nn * HC + l15;                   // global h col (D side)

    const float bir = b_ih[dcol], biz = b_ih[HID + dcol], bin_ = b_ih[2 * HID + dcol];
    const float bhr = b_hh[dcol], bhz = b_hh[HID + dcol], bhn  = b_hh[2 * HID + dcol];

    int* const myCnt = cnt + bb * 32;                  // counters 128B apart
    float* const ys = out + HFIN;

    for (int t = 0; t < T_SEQ; ++t) {
        // ---------- input GEMM gi (independent of h(t-1)) ----------
        f32x4 aIr = {0,0,0,0}, aIz = {0,0,0,0}, aIn = {0,0,0,0};
        const float* xrow = ins + ((size_t)arow * T_SEQ + t) * HID + lg * 8;
        #pragma unroll
        for (int kt = 0; kt < 16; ++kt) {
            f32x4 x0 = *(const f32x4*)(xrow + kt * 32);
            f32x4 x1 = *(const f32x4*)(xrow + kt * 32 + 4);
            short8 af = pack8(x0[0], x0[1], x0[2], x0[3], x1[0], x1[1], x1[2], x1[3]);
            const int ko = kt * 32 + lg * 8;
            short8 b0 = *(const short8*)&ldsW[0][l15][ko];
            short8 b1 = *(const short8*)&ldsW[0][16 + l15][ko];
            short8 b2 = *(const short8*)&ldsW[0][32 + l15][ko];
            aIr = __builtin_amdgcn_mfma_f32_16x16x32_bf16(af, b0, aIr, 0, 0, 0);
            aIz = __builtin_amdgcn_mfma_f32_16x16x32_bf16(af, b1, aIz, 0, 0, 0);
            aIn = __builtin_amdgcn_mfma_f32_16x16x32_bf16(af, b2, aIn, 0, 0, 0);
        }

        // ---------- wait for h(t-1) from all 32 chunk-producers of this block ----------
        if (t > 0) {
            if (tid == 0) {
                while (__hip_atomic_load(myCnt, __ATOMIC_RELAXED,
                                         __HIP_MEMORY_SCOPE_AGENT) < G_N * t) { }
                __threadfence();   // acquire: invalidate stale L2 before h reads
            }
            __syncthreads();
        }

        // ---------- hidden GEMM gh ----------
        f32x4 aHr = {0,0,0,0}, aHz = {0,0,0,0}, aHn = {0,0,0,0};
        const float* hrow = (t == 0)
            ? (hidden + (size_t)arow * HID + lg * 8)
            : (ys + ((size_t)arow * T_SEQ + (t - 1)) * HID + lg * 8);
        const float am = resets[arow * T_SEQ + t] ? 0.f : 1.f;   // reset carry mask
        #pragma unroll
        for (int kt = 0; kt < 16; ++kt) {
            f32x4 h0 = *(const f32x4*)(hrow + kt * 32);
            f32x4 h1 = *(const f32x4*)(hrow + kt * 32 + 4);
            short8 af = pack8(am * h0[0], am * h0[1], am * h0[2], am * h0[3],
                              am * h1[0], am * h1[1], am * h1[2], am * h1[3]);
            const int ko = kt * 32 + lg * 8;
            short8 b0 = *(const short8*)&ldsW[1][l15][ko];
            short8 b1 = *(const short8*)&ldsW[1][16 + l15][ko];
            short8 b2 = *(const short8*)&ldsW[1][32 + l15][ko];
            aHr = __builtin_amdgcn_mfma_f32_16x16x32_bf16(af, b0, aHr, 0, 0, 0);
            aHz = __builtin_amdgcn_mfma_f32_16x16x32_bf16(af, b1, aHz, 0, 0, 0);
            aHn = __builtin_amdgcn_mfma_f32_16x16x32_bf16(af, b2, aHn, 0, 0, 0);
        }

        // ---------- gates + store (wave-local; D: col=lane&15, row=(lane>>4)*4+j) ----------
        #pragma unroll
        for (int j = 0; j < 4; ++j) {
            const int r_ = drow0 + j;
            const float hp0 = (t == 0)
                ? hidden[(size_t)r_ * HID + dcol]
                : ys[((size_t)r_ * T_SEQ + (t - 1)) * HID + dcol];
            const float hp = resets[r_ * T_SEQ + t] ? 0.f : hp0;
            const float gr = aIr[j] + bir + aHr[j] + bhr;
            const float rg = 1.f / (1.f + __expf(-gr));
            const float gz = aIz[j] + biz + aHz[j] + bhz;
            const float zg = 1.f / (1.f + __expf(-gz));
            float gn = aIn[j] + bin_ + rg * (aHn[j] + bhn);
            gn = fminf(fmaxf(gn, -15.f), 15.f);
            const float e2 = __expf(2.f * gn);
            const float ng = (e2 - 1.f) / (e2 + 1.f);
            const float hn = (1.f - zg) * ng + zg * hp;
            ys[((size_t)r_ * T_SEQ + t) * HID + dcol] = hn;
            if (t == T_SEQ - 1) out[(size_t)r_ * HID + dcol] = hn;
        }

        // ---------- publish h(t) ----------
        __syncthreads();  // all waves' stores drained (compiler emits vmcnt(0) before barrier)
        if (tid == 0) {
            __threadfence();  // release: write back dirty L2 so LLC holds fresh h(t)
            __hip_atomic_fetch_add(myCnt, 1, __ATOMIC_RELAXED, __HIP_MEMORY_SCOPE_AGENT);
        }
    }
}

extern "C" void kernel_launch(void* const* d_in, const int* in_sizes, int n_in,
                              void* d_out, int out_size, void* d_ws, size_t ws_size,
                              hipStream_t stream) {
    const float* hidden = (const float*)d_in[0];
    const float* ins    = (const float*)d_in[1];
    const int*   resets = (const int*)d_in[2];
    const float* W_ih   = (const float*)d_in[3];
    const float* W_hh   = (const float*)d_in[4];
    const float* b_ih   = (const float*)d_in[5];
    const float* b_hh   = (const float*)d_in[6];
    float* out = (float*)d_out;
    int* cnt = (int*)d_ws;

    init_counters<<<1, 64, 0, stream>>>(cnt);
    gru_scan<<<dim3(G_B * G_N), dim3(THREADS), 0, stream>>>(
        hidden, ins, resets, W_ih, W_hh, b_ih, b_hh, out, cnt);
}

// Round 4
// 4608.444 us; speedup vs baseline: 1.3197x; 1.3197x over previous
//
#include <hip/hip_runtime.h>
#include <hip/hip_bf16.h>
#include <stdint.h>

#define T_SEQ 512
#define HID   512
#define BATCH 128
#define G_B   8
#define G_N   32
#define BB    (BATCH / G_B)     // 16 batch rows per WG
#define HC    (HID / G_N)       // 16 h-cols per WG
#define NROW  (3 * HC)          // 48 W rows per matrix chunk
#define HFIN  (BATCH * HID)
#define WSTR  520               // LDS row stride in shorts (16B-aligned rows)

using f32x4  = __attribute__((ext_vector_type(4))) float;
using short8 = __attribute__((ext_vector_type(8))) short;
using bfs4   = __attribute__((ext_vector_type(4))) short;

__device__ __forceinline__ short8 pack8(float a0, float a1, float a2, float a3,
                                        float a4, float a5, float a6, float a7) {
    union { uint32_t u[4]; short8 s; } r;
    asm("v_cvt_pk_bf16_f32 %0, %1, %2" : "=v"(r.u[0]) : "v"(a0), "v"(a1));
    asm("v_cvt_pk_bf16_f32 %0, %1, %2" : "=v"(r.u[1]) : "v"(a2), "v"(a3));
    asm("v_cvt_pk_bf16_f32 %0, %1, %2" : "=v"(r.u[2]) : "v"(a4), "v"(a5));
    asm("v_cvt_pk_bf16_f32 %0, %1, %2" : "=v"(r.u[3]) : "v"(a6), "v"(a7));
    return r.s;
}

__device__ __forceinline__ uint16_t f2bf(float f) {  // RNE
    uint32_t u = __builtin_bit_cast(uint32_t, f);
    return (uint16_t)((u + 0x7fffu + ((u >> 16) & 1u)) >> 16);
}

__global__ void init_ws(int* c) { c[threadIdx.x] = 0; }

__global__ void __launch_bounds__(64, 1) gru_scan(
    const float* __restrict__ hidden,   // [B][H]
    const float* __restrict__ ins,      // [B][T][H]
    const int*   __restrict__ resets,   // [B][T]
    const float* __restrict__ W_ih,     // [3H][H]
    const float* __restrict__ W_hh,     // [3H][H]
    const float* __restrict__ b_ih,     // [3H]
    const float* __restrict__ b_hh,     // [3H]
    float* __restrict__ out,            // [B*H] h_final, then [B][T][H] ys
    int* __restrict__ flags,            // [G_B*32] per-WG step counters
    unsigned short* __restrict__ xb)    // [2][B][H] bf16 h exchange (ping-pong)
{
    __shared__ __align__(16) short ldsW[2][NROW][WSTR];   // ~97.5 KB

    const int wg   = blockIdx.x;
    const int bb   = wg & 7;            // batch block == XCD (round-robin dispatch)
    const int nn   = wg >> 3;           // h-col chunk 0..31
    const int lane = threadIdx.x;       // single wave
    const int l15  = lane & 15;
    const int lg   = lane >> 4;         // 0..3

    // ---- one-time: W chunks -> LDS (bf16) ----
    for (int idx = lane; idx < NROW * (HID / 4); idx += 64) {
        const int row = idx >> 7;              // 0..47
        const int k4  = (idx & 127) << 2;
        const int g   = row >> 4;              // gate 0..2 (r,z,n)
        const int i   = row & 15;
        const int grow = g * HID + nn * HC + i;
        f32x4 wi = *(const f32x4*)&W_ih[(size_t)grow * HID + k4];
        f32x4 wh = *(const f32x4*)&W_hh[(size_t)grow * HID + k4];
        bfs4 si = { (short)f2bf(wi[0]), (short)f2bf(wi[1]), (short)f2bf(wi[2]), (short)f2bf(wi[3]) };
        bfs4 sh = { (short)f2bf(wh[0]), (short)f2bf(wh[1]), (short)f2bf(wh[2]), (short)f2bf(wh[3]) };
        *(bfs4*)&ldsW[0][row][k4] = si;
        *(bfs4*)&ldsW[1][row][k4] = sh;
    }
    __syncthreads();

    const int arow  = bb * BB + l15;            // A-operand batch row
    const int drow0 = bb * BB + lg * 4;         // D-side batch row base
    const int dcol  = nn * HC + l15;            // D-side h col

    const float bir = b_ih[dcol], biz = b_ih[HID + dcol], bin_ = b_ih[2 * HID + dcol];
    const float bhr = b_hh[dcol], bhz = b_hh[HID + dcol], bhn  = b_hh[2 * HID + dcol];

    float hprev[4];                             // own h(t-1) at (drow0+j, dcol), f32
    #pragma unroll
    for (int j = 0; j < 4; ++j)
        hprev[j] = hidden[(size_t)(drow0 + j) * HID + dcol];

    float* const ys = out + HFIN;
    int* const myFlags = flags + bb * 32;

    for (int t = 0; t < T_SEQ; ++t) {
        // ---------- input GEMM gi (independent of h(t-1)) ----------
        f32x4 aIr = {0,0,0,0}, aIz = {0,0,0,0}, aIn = {0,0,0,0};
        const float* xrow = ins + ((size_t)arow * T_SEQ + t) * HID + lg * 8;
        #pragma unroll
        for (int kt = 0; kt < 16; ++kt) {
            f32x4 x0 = *(const f32x4*)(xrow + kt * 32);
            f32x4 x1 = *(const f32x4*)(xrow + kt * 32 + 4);
            short8 af = pack8(x0[0], x0[1], x0[2], x0[3], x1[0], x1[1], x1[2], x1[3]);
            const int ko = kt * 32 + lg * 8;
            aIr = __builtin_amdgcn_mfma_f32_16x16x32_bf16(af, *(const short8*)&ldsW[0][l15][ko], aIr, 0, 0, 0);
            aIz = __builtin_amdgcn_mfma_f32_16x16x32_bf16(af, *(const short8*)&ldsW[0][16 + l15][ko], aIz, 0, 0, 0);
            aIn = __builtin_amdgcn_mfma_f32_16x16x32_bf16(af, *(const short8*)&ldsW[0][32 + l15][ko], aIn, 0, 0, 0);
        }

        const int rstA = resets[(size_t)arow * T_SEQ + t];

        // ---------- wait until all 32 producers of this block published h(t-1) ----------
        if (t > 0) {
            int* fl = myFlags + (lane & 31);
            while (__hip_atomic_load(fl, __ATOMIC_RELAXED, __HIP_MEMORY_SCOPE_AGENT) < t) { }
        }

        // ---------- load h(t-1) as bf16 A-fragments (coherent, bypass L2) ----------
        short8 ah[16];
        if (t == 0) {
            const float* hrow = hidden + (size_t)arow * HID + lg * 8;
            const float am = rstA ? 0.f : 1.f;
            #pragma unroll
            for (int kt = 0; kt < 16; ++kt) {
                f32x4 h0 = *(const f32x4*)(hrow + kt * 32);
                f32x4 h1 = *(const f32x4*)(hrow + kt * 32 + 4);
                ah[kt] = pack8(am * h0[0], am * h0[1], am * h0[2], am * h0[3],
                               am * h1[0], am * h1[1], am * h1[2], am * h1[3]);
            }
        } else {
            const unsigned short* hb =
                xb + (size_t)((t - 1) & 1) * HFIN + (size_t)arow * HID + lg * 8;
#define LOADH(K, OFFS) \
    asm volatile("global_load_dwordx4 %0, %1, off offset:" OFFS " sc0 sc1" \
                 : "=v"(ah[K]) : "v"(hb) : "memory")
            LOADH(0, "0");    LOADH(1, "64");   LOADH(2, "128");  LOADH(3, "192");
            LOADH(4, "256");  LOADH(5, "320");  LOADH(6, "384");  LOADH(7, "448");
            LOADH(8, "512");  LOADH(9, "576");  LOADH(10, "640"); LOADH(11, "704");
            LOADH(12, "768"); LOADH(13, "832"); LOADH(14, "896"); LOADH(15, "960");
#undef LOADH
            asm volatile("s_waitcnt vmcnt(0)" ::: "memory");
            __builtin_amdgcn_sched_barrier(0);
            if (rstA) {
                const short8 z8 = {0,0,0,0,0,0,0,0};
                #pragma unroll
                for (int kt = 0; kt < 16; ++kt) ah[kt] = z8;
            }
        }

        // ---------- hidden GEMM gh ----------
        f32x4 aHr = {0,0,0,0}, aHz = {0,0,0,0}, aHn = {0,0,0,0};
        #pragma unroll
        for (int kt = 0; kt < 16; ++kt) {
            const int ko = kt * 32 + lg * 8;
            aHr = __builtin_amdgcn_mfma_f32_16x16x32_bf16(ah[kt], *(const short8*)&ldsW[1][l15][ko], aHr, 0, 0, 0);
            aHz = __builtin_amdgcn_mfma_f32_16x16x32_bf16(ah[kt], *(const short8*)&ldsW[1][16 + l15][ko], aHz, 0, 0, 0);
            aHn = __builtin_amdgcn_mfma_f32_16x16x32_bf16(ah[kt], *(const short8*)&ldsW[1][32 + l15][ko], aHn, 0, 0, 0);
        }

        // ---------- gates + stores (D: col=lane&15, row=(lane>>4)*4+j) ----------
        #pragma unroll
        for (int j = 0; j < 4; ++j) {
            const int r_ = drow0 + j;
            const int rstD = resets[(size_t)r_ * T_SEQ + t];
            const float hp = rstD ? 0.f : hprev[j];
            const float gr = aIr[j] + bir + aHr[j] + bhr;
            const float rg = 1.f / (1.f + __expf(-gr));
            const float gz = aIz[j] + biz + aHz[j] + bhz;
            const float zg = 1.f / (1.f + __expf(-gz));
            float gn = aIn[j] + bin_ + rg * (aHn[j] + bhn);
            gn = fminf(fmaxf(gn, -15.f), 15.f);
            const float e2 = __expf(2.f * gn);
            const float ng = (e2 - 1.f) / (e2 + 1.f);
            const float hn = (1.f - zg) * ng + zg * hp;
            hprev[j] = hn;
            ys[((size_t)r_ * T_SEQ + t) * HID + dcol] = hn;
            if (t == T_SEQ - 1) {
                out[(size_t)r_ * HID + dcol] = hn;
            } else {
                uint32_t v = f2bf(hn);
                unsigned short* p = xb + (size_t)(t & 1) * HFIN + (size_t)r_ * HID + dcol;
                asm volatile("global_store_short %0, %1, off sc0 sc1"
                             :: "v"(p), "v"(v) : "memory");
            }
        }

        // ---------- publish h(t): drain data stores, then set flag ----------
        if (t < T_SEQ - 1) {
            asm volatile("s_waitcnt vmcnt(0)" ::: "memory");
            if (lane == 0)
                __hip_atomic_store(&myFlags[nn], t + 1,
                                   __ATOMIC_RELAXED, __HIP_MEMORY_SCOPE_AGENT);
        }
    }
}

extern "C" void kernel_launch(void* const* d_in, const int* in_sizes, int n_in,
                              void* d_out, int out_size, void* d_ws, size_t ws_size,
                              hipStream_t stream) {
    const float* hidden = (const float*)d_in[0];
    const float* ins    = (const float*)d_in[1];
    const int*   resets = (const int*)d_in[2];
    const float* W_ih   = (const float*)d_in[3];
    const float* W_hh   = (const float*)d_in[4];
    const float* b_ih   = (const float*)d_in[5];
    const float* b_hh   = (const float*)d_in[6];
    float* out = (float*)d_out;
    int* flags = (int*)d_ws;
    unsigned short* xb = (unsigned short*)((char*)d_ws + 1024);

    init_ws<<<1, 256, 0, stream>>>(flags);
    gru_scan<<<dim3(G_B * G_N), dim3(64), 0, stream>>>(
        hidden, ins, resets, W_ih, W_hh, b_ih, b_hh, out, flags, xb);
}